// Round 1
// baseline (999.796 us; speedup 1.0000x reference)
//
#include <hip/hip_runtime.h>
#include <stdint.h>

// InstantNGP hash-grid embedding, MI355X baseline.
// Parallelization: one thread per (point, level); level = tid & 15.
//  - output writes: float2 per lane, wave-contiguous 512 B -> perfectly coalesced
//  - gathers: 8 random float2 loads per thread from the level's 4 MB table
//  - low VGPR -> high occupancy -> many outstanding gathers (latency hiding)

#define N_LEVELS   16
#define LOG2_T     19
#define TABLE_SIZE (1u << LOG2_T)
#define HASH_MASK  (TABLE_SIZE - 1u)
#define P1 2654435761u
#define P2 805459861u

// resolutions: floor(16 * 2^(i/3))
__constant__ int   c_res[N_LEVELS]   = {16, 20, 25, 32, 40, 50, 64, 80,
                                        101, 128, 161, 203, 256, 322, 406, 512};
// scale = res/2 (exactly representable fp32 for all levels);
// rel = (x+1)*scale matches reference (x+1)/(2/res) to <=1 ulp.
__constant__ float c_scale[N_LEVELS] = {8.0f, 10.0f, 12.5f, 16.0f, 20.0f, 25.0f,
                                        32.0f, 40.0f, 50.5f, 64.0f, 80.5f, 101.5f,
                                        128.0f, 161.0f, 203.0f, 256.0f};

__global__ __launch_bounds__(256) void hash_embed_kernel(
    const float* __restrict__ x,
    const float* __restrict__ emb,
    float* __restrict__ out,
    int npts)
{
    int t = blockIdx.x * 256 + threadIdx.x;
    int l = t & (N_LEVELS - 1);
    int b = t >> 4;
    if (b >= npts) return;

    // 16 consecutive lanes share one point; redundant loads hit L1/broadcast.
    size_t xb = (size_t)b * 3;
    float xx = x[xb + 0];
    float xy = x[xb + 1];
    float xz = x[xb + 2];

    float fres  = (float)c_res[l];
    float scale = c_scale[l];
    float hi    = fres - 1.0f;

    float rx = (xx + 1.0f) * scale;
    float ry = (xy + 1.0f) * scale;
    float rz = (xz + 1.0f) * scale;

    float fx = fminf(fmaxf(floorf(rx), 0.0f), hi);
    float fy = fminf(fmaxf(floorf(ry), 0.0f), hi);
    float fz = fminf(fmaxf(floorf(rz), 0.0f), hi);

    float wx = rx - fx, wy = ry - fy, wz = rz - fz;

    uint32_t ix = (uint32_t)fx, iy = (uint32_t)fy, iz = (uint32_t)fz;

    // hash components per axis for the two corner values along that axis
    uint32_t a0 = ix,      a1 = ix + 1u;   // prime[0] == 1
    uint32_t b0 = iy * P1, b1 = b0 + P1;
    uint32_t c0 = iz * P2, c1 = c0 + P2;

    const float2* __restrict__ tb =
        (const float2*)emb + (size_t)l * TABLE_SIZE;

    // corner k: bits (k, k>>1, k>>2) select (x, y, z) offsets
    uint32_t h0 = (a0 ^ b0 ^ c0) & HASH_MASK;
    uint32_t h1 = (a1 ^ b0 ^ c0) & HASH_MASK;
    uint32_t h2 = (a0 ^ b1 ^ c0) & HASH_MASK;
    uint32_t h3 = (a1 ^ b1 ^ c0) & HASH_MASK;
    uint32_t h4 = (a0 ^ b0 ^ c1) & HASH_MASK;
    uint32_t h5 = (a1 ^ b0 ^ c1) & HASH_MASK;
    uint32_t h6 = (a0 ^ b1 ^ c1) & HASH_MASK;
    uint32_t h7 = (a1 ^ b1 ^ c1) & HASH_MASK;

    // issue all 8 gathers before the weight math (ILP / latency overlap)
    float2 v0 = tb[h0];
    float2 v1 = tb[h1];
    float2 v2 = tb[h2];
    float2 v3 = tb[h3];
    float2 v4 = tb[h4];
    float2 v5 = tb[h5];
    float2 v6 = tb[h6];
    float2 v7 = tb[h7];

    float ux = 1.0f - wx, uy = 1.0f - wy, uz = 1.0f - wz;
    float w0 = ux * uy * uz;
    float w1 = wx * uy * uz;
    float w2 = ux * wy * uz;
    float w3 = wx * wy * uz;
    float w4 = ux * uy * wz;
    float w5 = wx * uy * wz;
    float w6 = ux * wy * wz;
    float w7 = wx * wy * wz;

    float o0 = w0 * v0.x;
    float o1 = w0 * v0.y;
    o0 += w1 * v1.x;  o1 += w1 * v1.y;
    o0 += w2 * v2.x;  o1 += w2 * v2.y;
    o0 += w3 * v3.x;  o1 += w3 * v3.y;
    o0 += w4 * v4.x;  o1 += w4 * v4.y;
    o0 += w5 * v5.x;  o1 += w5 * v5.y;
    o0 += w6 * v6.x;  o1 += w6 * v6.y;
    o0 += w7 * v7.x;  o1 += w7 * v7.y;

    // out is (B, 32) fp32 == (B, 16) float2; index b*16 + l -> coalesced
    ((float2*)out)[(size_t)b * N_LEVELS + l] = make_float2(o0, o1);
}

extern "C" void kernel_launch(void* const* d_in, const int* in_sizes, int n_in,
                              void* d_out, int out_size, void* d_ws, size_t ws_size,
                              hipStream_t stream)
{
    const float* x   = (const float*)d_in[0];
    const float* emb = (const float*)d_in[1];
    float*       out = (float*)d_out;

    int npts   = in_sizes[0] / 3;
    int total  = npts * N_LEVELS;
    int blocks = (total + 255) / 256;

    hipLaunchKernelGGL(hash_embed_kernel, dim3(blocks), dim3(256), 0, stream,
                       x, emb, out, npts);
}

// Round 2
// 555.819 us; speedup vs baseline: 1.7988x; 1.7988x over previous
//
#include <hip/hip_runtime.h>
#include <stdint.h>

// InstantNGP hash-grid embedding, round 2: level-phased execution.
// Gather kernel: grid.y = level (dispatch order x-fastest -> levels sweep
// 0..15 in phases; only ~1-2 of the 4MB tables active chip-wide at a time,
// so the active table is L2-resident per XCD -> gathers are L2 hits, not
// ~900cy deep misses). 2 points/thread -> 16 outstanding gathers/lane.
// Writes level-major tmp (coalesced), then an LDS-tile transpose produces
// the point-major output layout.

#define N_LEVELS   16
#define LOG2_T     19
#define TABLE_SIZE (1u << LOG2_T)
#define HASH_MASK  (TABLE_SIZE - 1u)
#define P1 2654435761u
#define P2 805459861u

// resolutions: floor(16 * 2^(i/3))
__constant__ int   c_res[N_LEVELS]   = {16, 20, 25, 32, 40, 50, 64, 80,
                                        101, 128, 161, 203, 256, 322, 406, 512};
// scale = res/2 (exact in fp32); rel=(x+1)*scale matches ref to <=1 ulp.
__constant__ float c_scale[N_LEVELS] = {8.0f, 10.0f, 12.5f, 16.0f, 20.0f, 25.0f,
                                        32.0f, 40.0f, 50.5f, 64.0f, 80.5f, 101.5f,
                                        128.0f, 161.0f, 203.0f, 256.0f};

__device__ __forceinline__ float2 embed_point(
    const float2* __restrict__ tb,
    float xx, float xy, float xz, float scale, float hi)
{
    float rx = (xx + 1.0f) * scale;
    float ry = (xy + 1.0f) * scale;
    float rz = (xz + 1.0f) * scale;

    float fx = fminf(fmaxf(floorf(rx), 0.0f), hi);
    float fy = fminf(fmaxf(floorf(ry), 0.0f), hi);
    float fz = fminf(fmaxf(floorf(rz), 0.0f), hi);

    float wx = rx - fx, wy = ry - fy, wz = rz - fz;

    uint32_t ix = (uint32_t)fx, iy = (uint32_t)fy, iz = (uint32_t)fz;
    uint32_t a0 = ix,      a1 = ix + 1u;   // prime[0] == 1
    uint32_t b0 = iy * P1, b1 = b0 + P1;
    uint32_t c0 = iz * P2, c1 = c0 + P2;

    uint32_t h0 = (a0 ^ b0 ^ c0) & HASH_MASK;
    uint32_t h1 = (a1 ^ b0 ^ c0) & HASH_MASK;
    uint32_t h2 = (a0 ^ b1 ^ c0) & HASH_MASK;
    uint32_t h3 = (a1 ^ b1 ^ c0) & HASH_MASK;
    uint32_t h4 = (a0 ^ b0 ^ c1) & HASH_MASK;
    uint32_t h5 = (a1 ^ b0 ^ c1) & HASH_MASK;
    uint32_t h6 = (a0 ^ b1 ^ c1) & HASH_MASK;
    uint32_t h7 = (a1 ^ b1 ^ c1) & HASH_MASK;

    float2 v0 = tb[h0];
    float2 v1 = tb[h1];
    float2 v2 = tb[h2];
    float2 v3 = tb[h3];
    float2 v4 = tb[h4];
    float2 v5 = tb[h5];
    float2 v6 = tb[h6];
    float2 v7 = tb[h7];

    float ux = 1.0f - wx, uy = 1.0f - wy, uz = 1.0f - wz;
    float w0 = ux * uy * uz;
    float w1 = wx * uy * uz;
    float w2 = ux * wy * uz;
    float w3 = wx * wy * uz;
    float w4 = ux * uy * wz;
    float w5 = wx * uy * wz;
    float w6 = ux * wy * wz;
    float w7 = wx * wy * wz;

    float o0 = w0 * v0.x + w1 * v1.x + w2 * v2.x + w3 * v3.x
             + w4 * v4.x + w5 * v5.x + w6 * v6.x + w7 * v7.x;
    float o1 = w0 * v0.y + w1 * v1.y + w2 * v2.y + w3 * v3.y
             + w4 * v4.y + w5 * v5.y + w6 * v6.y + w7 * v7.y;
    return make_float2(o0, o1);
}

// DIRECT=false: dst = tmp, level-major: tmp[l*npts + b]   (coalesced)
// DIRECT=true : dst = out, point-major: out[b*16 + l]     (scatter fallback)
template<bool DIRECT>
__global__ __launch_bounds__(256) void hash_embed_lvl(
    const float* __restrict__ x,
    const float* __restrict__ emb,
    float2* __restrict__ dst,
    int npts)
{
    const int l  = blockIdx.y;
    const int bA = blockIdx.x * 512 + threadIdx.x;
    const int bB = bA + 256;

    const float scale = c_scale[l];
    const float hi    = (float)c_res[l] - 1.0f;
    const float2* __restrict__ tb = (const float2*)emb + (size_t)l * TABLE_SIZE;

    if (bA < npts) {
        size_t xb = (size_t)bA * 3;
        float2 r = embed_point(tb, x[xb], x[xb + 1], x[xb + 2], scale, hi);
        if (DIRECT) dst[(size_t)bA * N_LEVELS + l] = r;
        else        dst[(size_t)l * npts + bA]     = r;
    }
    if (bB < npts) {
        size_t xb = (size_t)bB * 3;
        float2 r = embed_point(tb, x[xb], x[xb + 1], x[xb + 2], scale, hi);
        if (DIRECT) dst[(size_t)bB * N_LEVELS + l] = r;
        else        dst[(size_t)l * npts + bB]     = r;
    }
}

// tmp[l][b] (float2) -> out[b][l] (float2), 64-point x 16-level LDS tiles.
__global__ __launch_bounds__(256) void transpose_lvl(
    const float2* __restrict__ tmp,
    float2* __restrict__ out,
    int npts)
{
    __shared__ float2 sm[64][N_LEVELS + 1];   // +1 pad to break bank stride

    const int b0  = blockIdx.x * 64;
    const int p   = threadIdx.x & 63;
    const int lq  = threadIdx.x >> 6;         // 0..3

    #pragma unroll
    for (int i = 0; i < 4; ++i) {
        int l = lq * 4 + i;
        int b = b0 + p;
        if (b < npts) sm[p][l] = tmp[(size_t)l * npts + b];
    }
    __syncthreads();

    #pragma unroll
    for (int k = 0; k < 4; ++k) {
        int q  = threadIdx.x + k * 256;       // 0..1023
        int pp = q >> 4;
        int ll = q & 15;
        int b  = b0 + pp;
        if (b < npts)
            out[(size_t)b * N_LEVELS + ll] = sm[pp][ll];
    }
}

extern "C" void kernel_launch(void* const* d_in, const int* in_sizes, int n_in,
                              void* d_out, int out_size, void* d_ws, size_t ws_size,
                              hipStream_t stream)
{
    const float* x   = (const float*)d_in[0];
    const float* emb = (const float*)d_in[1];
    float2*      out = (float2*)d_out;

    int npts = in_sizes[0] / 3;
    size_t tmp_bytes = (size_t)npts * N_LEVELS * sizeof(float2);

    dim3 grid((npts + 511) / 512, N_LEVELS);

    if (ws_size >= tmp_bytes) {
        float2* tmp = (float2*)d_ws;
        hipLaunchKernelGGL((hash_embed_lvl<false>), grid, dim3(256), 0, stream,
                           x, emb, tmp, npts);
        hipLaunchKernelGGL(transpose_lvl, dim3((npts + 63) / 64), dim3(256), 0, stream,
                           tmp, out, npts);
    } else {
        hipLaunchKernelGGL((hash_embed_lvl<true>), grid, dim3(256), 0, stream,
                           x, emb, out, npts);
    }
}

// Round 3
// 493.753 us; speedup vs baseline: 2.0249x; 1.1257x over previous
//
#include <hip/hip_runtime.h>
#include <hip/hip_fp16.h>
#include <stdint.h>

// InstantNGP hash-grid embedding, round 3.
// Bottleneck (round 2 counters): L2 request rate ~0.58 req/cy/CU with 134M
// random 8B gathers. Attack: (1) levels 0-7 re-staged as DENSE fp16 grids ->
// x-adjacent corners share cache lines (8 -> ~4.5 L2 reqs/pt) and coarse
// arrays become L1-resident; (2) hash tables pre-converted to fp16 (2MB ->
// fully L2-resident per XCD during its phase); (3) half2 tmp + tiled LDS
// transpose for the point-major output.

#define N_LEVELS   16
#define LOG2_T     19
#define TABLE_SIZE (1u << LOG2_T)
#define HASH_MASK  (TABLE_SIZE - 1u)
#define P1 2654435761u
#define P2 805459861u
#define N_DENSE    8          // levels 0..7: res<=80 -> (R+1)^3 <= 531441

__constant__ int   c_res[N_LEVELS]   = {16, 20, 25, 32, 40, 50, 64, 80,
                                        101, 128, 161, 203, 256, 322, 406, 512};
// scale = res/2 (exact fp32); rel=(x+1)*scale matches ref to <=1 ulp.
__constant__ float c_scale[N_LEVELS] = {8.0f, 10.0f, 12.5f, 16.0f, 20.0f, 25.0f,
                                        32.0f, 40.0f, 50.5f, 64.0f, 80.5f, 101.5f,
                                        128.0f, 161.0f, 203.0f, 256.0f};
// dense dims S=R+1 and prefix offsets (half2 elements) for levels 0..7
__constant__ uint32_t c_dim[N_DENSE]  = {17, 21, 26, 33, 41, 51, 65, 81};
__constant__ uint32_t c_doff[N_DENSE] = {0, 4913, 14174, 31750,
                                         67687, 136608, 269259, 543884};
#define DENSE_TOTAL 1075325u

// ---------------- pass 0a: fp16-convert hash tables (levels 8..15) ---------
__global__ __launch_bounds__(256) void conv_hash(
    const float2* __restrict__ emb, uint32_t* __restrict__ ht, int total)
{
    int i = blockIdx.x * 256 + threadIdx.x;
    if (i >= total) return;
    float2 v = emb[(size_t)N_DENSE * TABLE_SIZE + i];   // levels 8..15 contiguous
    __half2 h = __float22half2_rn(v);
    ht[i] = *(uint32_t*)&h;
}

// ---------------- pass 0b: build dense fp16 grids (levels 0..7) ------------
__global__ __launch_bounds__(256) void conv_dense(
    const float2* __restrict__ emb, uint32_t* __restrict__ dn)
{
    int l = blockIdx.y;
    uint32_t v = blockIdx.x * 256 + threadIdx.x;
    uint32_t S = c_dim[l];
    if (v >= S * S * S) return;
    uint32_t ix = v % S;
    uint32_t r  = v / S;
    uint32_t iy = r % S;
    uint32_t iz = r / S;
    uint32_t h  = (ix ^ (iy * P1) ^ (iz * P2)) & HASH_MASK;
    float2 val  = emb[(size_t)l * TABLE_SIZE + h];
    __half2 hv  = __float22half2_rn(val);
    dn[c_doff[l] + v] = *(uint32_t*)&hv;
}

// ---------------- gather core ----------------------------------------------
__device__ __forceinline__ void do_point(
    int l, int b, int npts,
    const float* __restrict__ x,
    const uint32_t* __restrict__ ht,
    const uint32_t* __restrict__ dn,
    uint32_t* __restrict__ tmp)
{
    if (b >= npts) return;
    size_t xb = (size_t)b * 3;
    float xx = x[xb], xy = x[xb + 1], xz = x[xb + 2];

    float scale = c_scale[l];
    float hi    = (float)c_res[l] - 1.0f;

    float rx = (xx + 1.0f) * scale;
    float ry = (xy + 1.0f) * scale;
    float rz = (xz + 1.0f) * scale;

    float fx = fminf(fmaxf(floorf(rx), 0.0f), hi);
    float fy = fminf(fmaxf(floorf(ry), 0.0f), hi);
    float fz = fminf(fmaxf(floorf(rz), 0.0f), hi);

    float wx = rx - fx, wy = ry - fy, wz = rz - fz;
    uint32_t ix = (uint32_t)fx, iy = (uint32_t)fy, iz = (uint32_t)fz;

    uint32_t u0, u1, u2, u3, u4, u5, u6, u7;
    if (l < N_DENSE) {                       // dense path: x-pairs line-adjacent
        uint32_t S    = c_dim[l];
        uint32_t base = c_doff[l] + (iz * S + iy) * S + ix;
        uint32_t S2   = S * S;
        u0 = dn[base];           u1 = dn[base + 1];
        u2 = dn[base + S];       u3 = dn[base + S + 1];
        u4 = dn[base + S2];      u5 = dn[base + S2 + 1];
        u6 = dn[base + S2 + S];  u7 = dn[base + S2 + S + 1];
    } else {                                  // hash path (fp16 table, 2MB)
        const uint32_t* __restrict__ tb = ht + (size_t)(l - N_DENSE) * TABLE_SIZE;
        uint32_t a0 = ix,      a1 = ix + 1u;  // prime[0]==1
        uint32_t b0 = iy * P1, b1 = b0 + P1;
        uint32_t c0 = iz * P2, c1 = c0 + P2;
        u0 = tb[(a0 ^ b0 ^ c0) & HASH_MASK];
        u1 = tb[(a1 ^ b0 ^ c0) & HASH_MASK];
        u2 = tb[(a0 ^ b1 ^ c0) & HASH_MASK];
        u3 = tb[(a1 ^ b1 ^ c0) & HASH_MASK];
        u4 = tb[(a0 ^ b0 ^ c1) & HASH_MASK];
        u5 = tb[(a1 ^ b0 ^ c1) & HASH_MASK];
        u6 = tb[(a0 ^ b1 ^ c1) & HASH_MASK];
        u7 = tb[(a1 ^ b1 ^ c1) & HASH_MASK];
    }

    float2 v0 = __half22float2(*(__half2*)&u0);
    float2 v1 = __half22float2(*(__half2*)&u1);
    float2 v2 = __half22float2(*(__half2*)&u2);
    float2 v3 = __half22float2(*(__half2*)&u3);
    float2 v4 = __half22float2(*(__half2*)&u4);
    float2 v5 = __half22float2(*(__half2*)&u5);
    float2 v6 = __half22float2(*(__half2*)&u6);
    float2 v7 = __half22float2(*(__half2*)&u7);

    float ux = 1.0f - wx, uy = 1.0f - wy, uz = 1.0f - wz;
    float w0 = ux * uy * uz, w1 = wx * uy * uz;
    float w2 = ux * wy * uz, w3 = wx * wy * uz;
    float w4 = ux * uy * wz, w5 = wx * uy * wz;
    float w6 = ux * wy * wz, w7 = wx * wy * wz;

    float o0 = w0 * v0.x + w1 * v1.x + w2 * v2.x + w3 * v3.x
             + w4 * v4.x + w5 * v5.x + w6 * v6.x + w7 * v7.x;
    float o1 = w0 * v0.y + w1 * v1.y + w2 * v2.y + w3 * v3.y
             + w4 * v4.y + w5 * v5.y + w6 * v6.y + w7 * v7.y;

    __half2 r = __float22half2_rn(make_float2(o0, o1));
    tmp[(size_t)l * npts + b] = *(uint32_t*)&r;
}

// grid.y = level (dispatch x-fastest -> level phases); 2 points/thread.
__global__ __launch_bounds__(256) void gather_lvl(
    const float* __restrict__ x,
    const uint32_t* __restrict__ ht,
    const uint32_t* __restrict__ dn,
    uint32_t* __restrict__ tmp, int npts)
{
    const int l  = blockIdx.y;
    const int bA = blockIdx.x * 512 + threadIdx.x;
    do_point(l, bA,       npts, x, ht, dn, tmp);
    do_point(l, bA + 256, npts, x, ht, dn, tmp);
}

// ---------------- pass 2: tmp[l][b] (half2) -> out[b][l] (float2) ----------
__global__ __launch_bounds__(256) void transpose_k(
    const uint32_t* __restrict__ tmp, float4* __restrict__ out4, int npts)
{
    __shared__ uint32_t sm[N_LEVELS][514];    // pad 2 -> <=2-way bank conflicts

    const int b0 = blockIdx.x * 512;
    const int t  = threadIdx.x;

    if (b0 + 512 <= npts) {
        #pragma unroll
        for (int l = 0; l < N_LEVELS; ++l) {
            uint2 u = *(const uint2*)&tmp[(size_t)l * npts + b0 + 2 * t];
            sm[l][2 * t]     = u.x;
            sm[l][2 * t + 1] = u.y;
        }
        __syncthreads();
        #pragma unroll
        for (int k = 0; k < 16; ++k) {
            int q = k * 256 + t;              // float4 index in tile (0..4095)
            int p = q >> 3;                   // point in tile
            int j = q & 7;                    // float4 within point
            uint32_t a = sm[2 * j][p], b = sm[2 * j + 1][p];
            float2 f0 = __half22float2(*(__half2*)&a);
            float2 f1 = __half22float2(*(__half2*)&b);
            out4[(size_t)(b0 + p) * 8 + j] = make_float4(f0.x, f0.y, f1.x, f1.y);
        }
    } else {                                  // guarded tail tile
        for (int l = 0; l < N_LEVELS; ++l) {
            for (int s = 0; s < 2; ++s) {
                int b = b0 + 2 * t + s;
                if (b < npts) sm[l][2 * t + s] = tmp[(size_t)l * npts + b];
            }
        }
        __syncthreads();
        for (int k = 0; k < 16; ++k) {
            int q = k * 256 + t;
            int p = q >> 3, j = q & 7;
            if (b0 + p < npts) {
                uint32_t a = sm[2 * j][p], b = sm[2 * j + 1][p];
                float2 f0 = __half22float2(*(__half2*)&a);
                float2 f1 = __half22float2(*(__half2*)&b);
                out4[(size_t)(b0 + p) * 8 + j] = make_float4(f0.x, f0.y, f1.x, f1.y);
            }
        }
    }
}

// ---------------- fallback (no workspace): direct fp32, point-major --------
__global__ __launch_bounds__(256) void hash_embed_direct(
    const float* __restrict__ x, const float* __restrict__ emb,
    float2* __restrict__ out, int npts)
{
    int t = blockIdx.x * 256 + threadIdx.x;
    int l = t & 15, b = t >> 4;
    if (b >= npts) return;
    size_t xb = (size_t)b * 3;
    float scale = c_scale[l], hi = (float)c_res[l] - 1.0f;
    float rx = (x[xb] + 1.0f) * scale, ry = (x[xb+1] + 1.0f) * scale, rz = (x[xb+2] + 1.0f) * scale;
    float fx = fminf(fmaxf(floorf(rx), 0.0f), hi);
    float fy = fminf(fmaxf(floorf(ry), 0.0f), hi);
    float fz = fminf(fmaxf(floorf(rz), 0.0f), hi);
    float wx = rx - fx, wy = ry - fy, wz = rz - fz;
    uint32_t ix = (uint32_t)fx, iy = (uint32_t)fy, iz = (uint32_t)fz;
    uint32_t a0 = ix, a1 = ix + 1u, b0 = iy * P1, b1 = b0 + P1, c0 = iz * P2, c1 = c0 + P2;
    const float2* tb = (const float2*)emb + (size_t)l * TABLE_SIZE;
    float2 v0 = tb[(a0^b0^c0)&HASH_MASK], v1 = tb[(a1^b0^c0)&HASH_MASK];
    float2 v2 = tb[(a0^b1^c0)&HASH_MASK], v3 = tb[(a1^b1^c0)&HASH_MASK];
    float2 v4 = tb[(a0^b0^c1)&HASH_MASK], v5 = tb[(a1^b0^c1)&HASH_MASK];
    float2 v6 = tb[(a0^b1^c1)&HASH_MASK], v7 = tb[(a1^b1^c1)&HASH_MASK];
    float ux = 1.0f - wx, uy = 1.0f - wy, uz = 1.0f - wz;
    float w0 = ux*uy*uz, w1 = wx*uy*uz, w2 = ux*wy*uz, w3 = wx*wy*uz;
    float w4 = ux*uy*wz, w5 = wx*uy*wz, w6 = ux*wy*wz, w7 = wx*wy*wz;
    float o0 = w0*v0.x+w1*v1.x+w2*v2.x+w3*v3.x+w4*v4.x+w5*v5.x+w6*v6.x+w7*v7.x;
    float o1 = w0*v0.y+w1*v1.y+w2*v2.y+w3*v3.y+w4*v4.y+w5*v5.y+w6*v6.y+w7*v7.y;
    out[(size_t)b * N_LEVELS + l] = make_float2(o0, o1);
}

extern "C" void kernel_launch(void* const* d_in, const int* in_sizes, int n_in,
                              void* d_out, int out_size, void* d_ws, size_t ws_size,
                              hipStream_t stream)
{
    const float*  x   = (const float*)d_in[0];
    const float2* emb = (const float2*)d_in[1];
    int npts = in_sizes[0] / 3;

    size_t tmp_bytes = (size_t)npts * N_LEVELS * 4;        // half2 per (pt,lvl)
    size_t ht_bytes  = (size_t)N_DENSE * TABLE_SIZE * 4;   // 8 fp16 hash tables
    size_t dn_bytes  = (size_t)DENSE_TOTAL * 4;
    size_t need      = tmp_bytes + ht_bytes + dn_bytes;

    if (ws_size >= need) {
        uint32_t* tmp = (uint32_t*)d_ws;
        uint32_t* ht  = (uint32_t*)((char*)d_ws + tmp_bytes);
        uint32_t* dn  = (uint32_t*)((char*)d_ws + tmp_bytes + ht_bytes);

        int ht_total = N_DENSE * TABLE_SIZE;               // 4.19M entries
        hipLaunchKernelGGL(conv_hash, dim3((ht_total + 255) / 256), dim3(256),
                           0, stream, emb, ht, ht_total);
        hipLaunchKernelGGL(conv_dense, dim3(2077, N_DENSE), dim3(256),
                           0, stream, emb, dn);
        hipLaunchKernelGGL(gather_lvl, dim3((npts + 511) / 512, N_LEVELS), dim3(256),
                           0, stream, (const float*)x, ht, dn, tmp, npts);
        hipLaunchKernelGGL(transpose_k, dim3((npts + 511) / 512), dim3(256),
                           0, stream, tmp, (float4*)d_out, npts);
    } else {
        int total = npts * N_LEVELS;
        hipLaunchKernelGGL(hash_embed_direct, dim3((total + 255) / 256), dim3(256),
                           0, stream, (const float*)x, (const float*)emb,
                           (float2*)d_out, npts);
    }
}